// Round 8
// baseline (1005.608 us; speedup 1.0000x reference)
//
#include <hip/hip_runtime.h>
#include <math.h>

#define HDIM 128
#define EPSLN 1e-5f

// ---------------- graph preprocessing ----------------

__global__ __launch_bounds__(256) void count_k(const int* __restrict__ dst,
                                               int* __restrict__ counts, int E_) {
  int e = blockIdx.x * 256 + threadIdx.x;
  if (e < E_) atomicAdd(&counts[dst[e]], 1);
}

__global__ __launch_bounds__(256) void dinv_k(const int* __restrict__ counts,
                                              float* __restrict__ dinv, int n) {
  int i = blockIdx.x * 256 + threadIdx.x;
  if (i < n) dinv[i] = rsqrtf((float)(counts[i] + 1));  // +1 = self loop
}

// scan over counts -> exclusive rowptr.  CHUNK = 1024 elems per block (256 thr x 4)
__global__ __launch_bounds__(256) void scan1_k(const int* __restrict__ counts,
                                               int* __restrict__ bsum, int n) {
  __shared__ int sm[256];
  int t = threadIdx.x;
  int base = blockIdx.x * 1024;
  int s = 0;
  for (int i = 0; i < 4; i++) {
    int idx = base + t * 4 + i;
    if (idx < n) s += counts[idx];
  }
  sm[t] = s;
  __syncthreads();
  for (int off = 128; off; off >>= 1) {
    if (t < off) sm[t] += sm[t + off];
    __syncthreads();
  }
  if (t == 0) bsum[blockIdx.x] = sm[0];
}

__global__ __launch_bounds__(256) void scan2_k(int* __restrict__ bsum,
                                               int* __restrict__ rowptr, int G_, int n) {
  __shared__ int sm[256];
  int t = threadIdx.x;
  int orig = (t < G_) ? bsum[t] : 0;
  sm[t] = orig;
  __syncthreads();
  for (int off = 1; off < 256; off <<= 1) {
    int v = (t >= off) ? sm[t - off] : 0;
    __syncthreads();
    sm[t] += v;
    __syncthreads();
  }
  if (t < G_) bsum[t] = sm[t] - orig;  // exclusive prefix per block
  if (t == 0) rowptr[n] = sm[255];     // total = E (zero padded)
}

__global__ __launch_bounds__(256) void scan3_k(const int* __restrict__ counts,
                                               const int* __restrict__ bsum,
                                               int* __restrict__ rowptr,
                                               int* __restrict__ cursor, int n) {
  __shared__ int sm[256];
  int t = threadIdx.x;
  int base = blockIdx.x * 1024;
  int loc[4];
  int s = 0;
  for (int i = 0; i < 4; i++) {
    int idx = base + t * 4 + i;
    loc[i] = (idx < n) ? counts[idx] : 0;
    s += loc[i];
  }
  sm[t] = s;
  __syncthreads();
  int orig = s;
  for (int off = 1; off < 256; off <<= 1) {
    int v = (t >= off) ? sm[t - off] : 0;
    __syncthreads();
    sm[t] += v;
    __syncthreads();
  }
  int excl = sm[t] - orig + bsum[blockIdx.x];
  for (int i = 0; i < 4; i++) {
    int idx = base + t * 4 + i;
    if (idx < n) {
      rowptr[idx] = excl;
      cursor[idx] = excl;
      excl += loc[i];
    }
  }
}

// weight dinv[s]*dinv[d] is IMPLICIT (folded into gemm epilogue + agg epilogue),
// so fill writes only the column index: ONE random 64B line per edge instead of two.
__global__ __launch_bounds__(256) void fill_k(const int* __restrict__ src,
                                              const int* __restrict__ dst,
                                              int* __restrict__ cursor,
                                              int* __restrict__ colx, int E_) {
  int e = blockIdx.x * 256 + threadIdx.x;
  if (e < E_) {
    int s = src[e], d = dst[e];
    int slot = atomicAdd(&cursor[d], 1);
    colx[slot] = s;
  }
}

// ---------------- dense GEMM: Out[n x 128] = dinv ⊙ (A[n x 128] @ W[128 x 128]) ------
// block = 256 threads, 64 rows per block.  A tile staged in LDS (32 KB), W via L1/L2.
__global__ __launch_bounds__(256) void gemm_k(const float* __restrict__ A,
                                              const float* __restrict__ W,
                                              const float* __restrict__ dinv,
                                              float* __restrict__ Out, int n) {
  __shared__ float hs[64 * HDIM];
  int t = threadIdx.x;
  int rowbase = blockIdx.x * 64;
  const float4* A4 = (const float4*)(A + (size_t)rowbase * HDIM);
  for (int i = 0; i < 8; i++) {
    int fi = t + i * 256;              // float4 index within tile (32 per row)
    int row = rowbase + (fi >> 5);
    float4 v = make_float4(0.f, 0.f, 0.f, 0.f);
    if (row < n) v = A4[fi];
    ((float4*)hs)[fi] = v;
  }
  __syncthreads();

  int tc = t & 31;        // col group: cols 4*tc .. 4*tc+3
  int tr = t >> 5;        // row group: rows tr*8 .. tr*8+7
  float acc[8][4];
  for (int i = 0; i < 8; i++)
    for (int j = 0; j < 4; j++) acc[i][j] = 0.f;

  const float4* W4 = (const float4*)W;
  for (int k = 0; k < HDIM; k += 4) {
    float4 w0 = W4[(k + 0) * 32 + tc];
    float4 w1 = W4[(k + 1) * 32 + tc];
    float4 w2 = W4[(k + 2) * 32 + tc];
    float4 w3 = W4[(k + 3) * 32 + tc];
    for (int i = 0; i < 8; i++) {
      float4 h4 = *((const float4*)&hs[(tr * 8 + i) * HDIM + k]);
      acc[i][0] += h4.x * w0.x + h4.y * w1.x + h4.z * w2.x + h4.w * w3.x;
      acc[i][1] += h4.x * w0.y + h4.y * w1.y + h4.z * w2.y + h4.w * w3.y;
      acc[i][2] += h4.x * w0.z + h4.y * w1.z + h4.z * w2.z + h4.w * w3.z;
      acc[i][3] += h4.x * w0.w + h4.y * w1.w + h4.z * w2.w + h4.w * w3.w;
    }
  }
  for (int i = 0; i < 8; i++) {
    int row = rowbase + tr * 8 + i;
    if (row < n) {
      float dv = dinv[row];
      float4 o = make_float4(acc[i][0] * dv, acc[i][1] * dv, acc[i][2] * dv, acc[i][3] * dv);
      ((float4*)(Out + (size_t)row * HDIM))[tc] = o;
    }
  }
}

// ---------------- aggregation: one wave per dst node ----------------
// T is pre-scaled by dinv (T' = dinv ⊙ (A·W)).  out = dinv[d]*(T'[d] + Σ T'[src]) + b.
// MODE 0: + bias, relu, layernorm(g,b).   MODE 1: + bias only (emb output).
template <int MODE>
__global__ __launch_bounds__(256) void agg_k(const float* __restrict__ T,
                                             const int* __restrict__ rowptr,
                                             const int* __restrict__ colx,
                                             const float* __restrict__ dinv,
                                             const float* __restrict__ bias,
                                             const float* __restrict__ lng,
                                             const float* __restrict__ lnb,
                                             float* __restrict__ Out, int n) {
  int wid = (blockIdx.x * 256 + threadIdx.x) >> 6;
  int lane = threadIdx.x & 63;
  if (wid >= n) return;
  int i = wid;
  float di = dinv[i];
  // self term: T'[i]
  float2 a0 = ((const float2*)(T + (size_t)i * HDIM))[lane];
  float2 a1 = make_float2(0.f, 0.f);
  int beg = rowptr[i], end = rowptr[i + 1];
  int e = beg;
  // 2-way unroll: two independent row gathers in flight
  for (; e + 1 < end; e += 2) {
    int c0 = colx[e];
    int c1 = colx[e + 1];
    float2 v0 = ((const float2*)(T + (size_t)c0 * HDIM))[lane];
    float2 v1 = ((const float2*)(T + (size_t)c1 * HDIM))[lane];
    a0.x += v0.x; a0.y += v0.y;
    a1.x += v1.x; a1.y += v1.y;
  }
  if (e < end) {
    int c0 = colx[e];
    float2 v0 = ((const float2*)(T + (size_t)c0 * HDIM))[lane];
    a0.x += v0.x; a0.y += v0.y;
  }
  float2 bb = ((const float2*)bias)[lane];
  float2 acc;
  acc.x = (a0.x + a1.x) * di + bb.x;
  acc.y = (a0.y + a1.y) * di + bb.y;
  if (MODE == 0) {
    acc.x = fmaxf(acc.x, 0.f);
    acc.y = fmaxf(acc.y, 0.f);
    float s1 = acc.x + acc.y;
    float s2 = acc.x * acc.x + acc.y * acc.y;
    for (int off = 1; off < 64; off <<= 1) {
      s1 += __shfl_xor(s1, off);
      s2 += __shfl_xor(s2, off);
    }
    float mu = s1 * (1.f / 128.f);
    float var = s2 * (1.f / 128.f) - mu * mu;
    float r = rsqrtf(var + EPSLN);
    float2 gg = ((const float2*)lng)[lane];
    float2 b2 = ((const float2*)lnb)[lane];
    acc.x = (acc.x - mu) * r * gg.x + b2.x;
    acc.y = (acc.y - mu) * r * gg.y + b2.y;
  }
  ((float2*)(Out + (size_t)i * HDIM))[lane] = acc;
}

// ---------------- fused head: relu -> Linear(128) -> Linear(2) -> log_softmax ----------------
// Same register-blocked GEMM structure as gemm_k (W1 read once per BLOCK, not per node).
__global__ __launch_bounds__(256) void head_k(const float* __restrict__ emb,
                                              const float* __restrict__ W1_,
                                              const float* __restrict__ b1_,
                                              const float* __restrict__ W2_,
                                              const float* __restrict__ b2_,
                                              float* __restrict__ outp, int n) {
  __shared__ float hs[64 * HDIM];
  int t = threadIdx.x;
  int rowbase = blockIdx.x * 64;
  const float4* A4 = (const float4*)(emb + (size_t)rowbase * HDIM);
  for (int i = 0; i < 8; i++) {
    int fi = t + i * 256;
    int row = rowbase + (fi >> 5);
    float4 v = make_float4(0.f, 0.f, 0.f, 0.f);
    if (row < n) v = A4[fi];
    v.x = fmaxf(v.x, 0.f);  // relu while staging
    v.y = fmaxf(v.y, 0.f);
    v.z = fmaxf(v.z, 0.f);
    v.w = fmaxf(v.w, 0.f);
    ((float4*)hs)[fi] = v;
  }
  __syncthreads();

  int tc = t & 31;
  int tr = t >> 5;
  float acc[8][4];
  float4 binit = ((const float4*)b1_)[tc];
  for (int i = 0; i < 8; i++) {
    acc[i][0] = binit.x; acc[i][1] = binit.y; acc[i][2] = binit.z; acc[i][3] = binit.w;
  }

  const float4* W4 = (const float4*)W1_;
  for (int k = 0; k < HDIM; k += 4) {
    float4 w0 = W4[(k + 0) * 32 + tc];
    float4 w1 = W4[(k + 1) * 32 + tc];
    float4 w2 = W4[(k + 2) * 32 + tc];
    float4 w3 = W4[(k + 3) * 32 + tc];
    for (int i = 0; i < 8; i++) {
      float4 h4 = *((const float4*)&hs[(tr * 8 + i) * HDIM + k]);
      acc[i][0] += h4.x * w0.x + h4.y * w1.x + h4.z * w2.x + h4.w * w3.x;
      acc[i][1] += h4.x * w0.y + h4.y * w1.y + h4.z * w2.y + h4.w * w3.y;
      acc[i][2] += h4.x * w0.z + h4.y * w1.z + h4.z * w2.z + h4.w * w3.z;
      acc[i][3] += h4.x * w0.w + h4.y * w1.w + h4.z * w2.w + h4.w * w3.w;
    }
  }

  // second linear: z row dotted with W2 [128 x 2].  This thread owns cols 4*tc..4*tc+3.
  float2 w2c[4];
  for (int j = 0; j < 4; j++) w2c[j] = ((const float2*)W2_)[4 * tc + j];
  float o0[8], o1[8];
  for (int i = 0; i < 8; i++) {
    o0[i] = acc[i][0] * w2c[0].x + acc[i][1] * w2c[1].x + acc[i][2] * w2c[2].x + acc[i][3] * w2c[3].x;
    o1[i] = acc[i][0] * w2c[0].y + acc[i][1] * w2c[1].y + acc[i][2] * w2c[2].y + acc[i][3] * w2c[3].y;
  }
  // reduce across the 32 lanes sharing this tr (xor offsets < 32 stay within the half-wave)
  for (int off = 1; off < 32; off <<= 1) {
    for (int i = 0; i < 8; i++) {
      o0[i] += __shfl_xor(o0[i], off);
      o1[i] += __shfl_xor(o1[i], off);
    }
  }
  if (tc == 0) {
    float B0 = b2_[0], B1 = b2_[1];
    for (int i = 0; i < 8; i++) {
      int row = rowbase + tr * 8 + i;
      if (row < n) {
        float a = o0[i] + B0, b = o1[i] + B1;
        float m = fmaxf(a, b);
        float lse = m + logf(expf(a - m) + expf(b - m));
        outp[(size_t)row * 2 + 0] = a - lse;
        outp[(size_t)row * 2 + 1] = b - lse;
      }
    }
  }
}

// ---------------- launcher ----------------

extern "C" void kernel_launch(void* const* d_in, const int* in_sizes, int n_in,
                              void* d_out, int out_size, void* d_ws, size_t ws_size,
                              hipStream_t stream) {
  const float* x = (const float*)d_in[0];
  const int* ei = (const int*)d_in[1];
  const float* W1 = (const float*)d_in[2];
  const float* b1 = (const float*)d_in[3];
  const float* W2 = (const float*)d_in[4];
  const float* b2 = (const float*)d_in[5];
  const float* W3 = (const float*)d_in[6];
  const float* b3 = (const float*)d_in[7];
  const float* ln1g = (const float*)d_in[8];
  const float* ln1b = (const float*)d_in[9];
  const float* ln2g = (const float*)d_in[10];
  const float* ln2b = (const float*)d_in[11];
  const float* mpW1 = (const float*)d_in[12];
  const float* mpb1 = (const float*)d_in[13];
  const float* mpW2 = (const float*)d_in[14];
  const float* mpb2 = (const float*)d_in[15];

  const int N = in_sizes[0] / HDIM;
  const int E = in_sizes[1] / 2;
  const int* srcp = ei;
  const int* dstp = ei + E;

  // carve workspace
  char* p = (char*)d_ws;
  auto carve = [&](size_t bytes) {
    void* r = (void*)p;
    p += (bytes + 255) & ~(size_t)255;
    return r;
  };
  int* counts = (int*)carve((size_t)N * 4);
  int* rowptr = (int*)carve((size_t)(N + 1) * 4);
  int* cursor = (int*)carve((size_t)N * 4);
  int* bsum = (int*)carve(256 * 4);
  float* dinv = (float*)carve((size_t)N * 4);
  int* colx = (int*)carve((size_t)E * 4);
  float* bufA = (float*)carve((size_t)N * HDIM * 4);
  float* bufB = (float*)carve((size_t)N * HDIM * 4);

  float* emb = (float*)d_out;                    // N x 128
  float* logits = (float*)d_out + (size_t)N * HDIM;  // N x 2

  const int G = (N + 1023) / 1024;  // scan blocks (<= 256)

  hipMemsetAsync(counts, 0, (size_t)N * 4, stream);
  count_k<<<(E + 255) / 256, 256, 0, stream>>>(dstp, counts, E);
  dinv_k<<<(N + 255) / 256, 256, 0, stream>>>(counts, dinv, N);
  scan1_k<<<G, 256, 0, stream>>>(counts, bsum, N);
  scan2_k<<<1, 256, 0, stream>>>(bsum, rowptr, G, N);
  scan3_k<<<G, 256, 0, stream>>>(counts, bsum, rowptr, cursor, N);
  fill_k<<<(E + 255) / 256, 256, 0, stream>>>(srcp, dstp, cursor, colx, E);

  const int gemmG = (N + 63) / 64;
  const int aggG = (N * 64 + 255) / 256;

  // layer 1: x -> bufA (pre-scaled) -> (agg+relu+LN) bufB
  gemm_k<<<gemmG, 256, 0, stream>>>(x, W1, dinv, bufA, N);
  agg_k<0><<<aggG, 256, 0, stream>>>(bufA, rowptr, colx, dinv, b1, ln1g, ln1b, bufB, N);
  // layer 2
  gemm_k<<<gemmG, 256, 0, stream>>>(bufB, W2, dinv, bufA, N);
  agg_k<0><<<aggG, 256, 0, stream>>>(bufA, rowptr, colx, dinv, b2, ln2g, ln2b, bufB, N);
  // layer 3 -> emb (pre-relu) straight into d_out
  gemm_k<<<gemmG, 256, 0, stream>>>(bufB, W3, dinv, bufA, N);
  agg_k<1><<<aggG, 256, 0, stream>>>(bufA, rowptr, colx, dinv, b3, nullptr, nullptr, emb, N);
  // head (register-blocked, fused log-softmax)
  head_k<<<gemmG, 256, 0, stream>>>(emb, mpW1, mpb1, mpW2, mpb2, logits, N);
}

// Round 9
// 815.453 us; speedup vs baseline: 1.2332x; 1.2332x over previous
//
#include <hip/hip_runtime.h>
#include <math.h>

#define HDIM 128
#define EPSLN 1e-5f

// bf16 helpers: RNE float->bf16, exact bf16->float via bit ops
__device__ __forceinline__ unsigned short f2bf(float f) {
  unsigned int u = __float_as_uint(f);
  u = u + 0x7fffu + ((u >> 16) & 1u);
  return (unsigned short)(u >> 16);
}
__device__ __forceinline__ float bf_lo(unsigned int packed) {  // low bf16 -> f32
  return __uint_as_float(packed << 16);
}
__device__ __forceinline__ float bf_hi(unsigned int packed) {  // high bf16 -> f32
  return __uint_as_float(packed & 0xffff0000u);
}

// ---------------- graph preprocessing ----------------

__global__ __launch_bounds__(256) void count_k(const int* __restrict__ dst,
                                               int* __restrict__ counts, int E_) {
  int e = blockIdx.x * 256 + threadIdx.x;
  if (e < E_) atomicAdd(&counts[dst[e]], 1);
}

__global__ __launch_bounds__(256) void dinv_k(const int* __restrict__ counts,
                                              float* __restrict__ dinv, int n) {
  int i = blockIdx.x * 256 + threadIdx.x;
  if (i < n) dinv[i] = rsqrtf((float)(counts[i] + 1));  // +1 = self loop
}

// scan over counts -> exclusive rowptr.  CHUNK = 1024 elems per block (256 thr x 4)
__global__ __launch_bounds__(256) void scan1_k(const int* __restrict__ counts,
                                               int* __restrict__ bsum, int n) {
  __shared__ int sm[256];
  int t = threadIdx.x;
  int base = blockIdx.x * 1024;
  int s = 0;
  for (int i = 0; i < 4; i++) {
    int idx = base + t * 4 + i;
    if (idx < n) s += counts[idx];
  }
  sm[t] = s;
  __syncthreads();
  for (int off = 128; off; off >>= 1) {
    if (t < off) sm[t] += sm[t + off];
    __syncthreads();
  }
  if (t == 0) bsum[blockIdx.x] = sm[0];
}

__global__ __launch_bounds__(256) void scan2_k(int* __restrict__ bsum,
                                               int* __restrict__ rowptr, int G_, int n) {
  __shared__ int sm[256];
  int t = threadIdx.x;
  int orig = (t < G_) ? bsum[t] : 0;
  sm[t] = orig;
  __syncthreads();
  for (int off = 1; off < 256; off <<= 1) {
    int v = (t >= off) ? sm[t - off] : 0;
    __syncthreads();
    sm[t] += v;
    __syncthreads();
  }
  if (t < G_) bsum[t] = sm[t] - orig;  // exclusive prefix per block
  if (t == 0) rowptr[n] = sm[255];     // total = E (zero padded)
}

__global__ __launch_bounds__(256) void scan3_k(const int* __restrict__ counts,
                                               const int* __restrict__ bsum,
                                               int* __restrict__ rowptr,
                                               int* __restrict__ cursor, int n) {
  __shared__ int sm[256];
  int t = threadIdx.x;
  int base = blockIdx.x * 1024;
  int loc[4];
  int s = 0;
  for (int i = 0; i < 4; i++) {
    int idx = base + t * 4 + i;
    loc[i] = (idx < n) ? counts[idx] : 0;
    s += loc[i];
  }
  sm[t] = s;
  __syncthreads();
  int orig = s;
  for (int off = 1; off < 256; off <<= 1) {
    int v = (t >= off) ? sm[t - off] : 0;
    __syncthreads();
    sm[t] += v;
    __syncthreads();
  }
  int excl = sm[t] - orig + bsum[blockIdx.x];
  for (int i = 0; i < 4; i++) {
    int idx = base + t * 4 + i;
    if (idx < n) {
      rowptr[idx] = excl;
      cursor[idx] = excl;
      excl += loc[i];
    }
  }
}

// weight dinv[s]*dinv[d] is IMPLICIT (folded into gemm epilogue + agg epilogue),
// so fill writes only the column index.
__global__ __launch_bounds__(256) void fill_k(const int* __restrict__ src,
                                              const int* __restrict__ dst,
                                              int* __restrict__ cursor,
                                              int* __restrict__ colx, int E_) {
  int e = blockIdx.x * 256 + threadIdx.x;
  if (e < E_) {
    int s = src[e], d = dst[e];
    int slot = atomicAdd(&cursor[d], 1);
    colx[slot] = s;
  }
}

// ---------------- dense GEMM: T'[n x 128](bf16) = dinv ⊙ (A[n x 128] @ W[128 x 128]) --
// block = 256 threads, 64 rows per block.  A tile staged in LDS (32 KB), W via L1/L2.
// Epilogue converts to bf16 (RNE) -> halves the downstream gather bytes.
__global__ __launch_bounds__(256) void gemm_k(const float* __restrict__ A,
                                              const float* __restrict__ W,
                                              const float* __restrict__ dinv,
                                              unsigned short* __restrict__ Out, int n) {
  __shared__ float hs[64 * HDIM];
  int t = threadIdx.x;
  int rowbase = blockIdx.x * 64;
  const float4* A4 = (const float4*)(A + (size_t)rowbase * HDIM);
  for (int i = 0; i < 8; i++) {
    int fi = t + i * 256;              // float4 index within tile (32 per row)
    int row = rowbase + (fi >> 5);
    float4 v = make_float4(0.f, 0.f, 0.f, 0.f);
    if (row < n) v = A4[fi];
    ((float4*)hs)[fi] = v;
  }
  __syncthreads();

  int tc = t & 31;        // col group: cols 4*tc .. 4*tc+3
  int tr = t >> 5;        // row group: rows tr*8 .. tr*8+7
  float acc[8][4];
  for (int i = 0; i < 8; i++)
    for (int j = 0; j < 4; j++) acc[i][j] = 0.f;

  const float4* W4 = (const float4*)W;
  for (int k = 0; k < HDIM; k += 4) {
    float4 w0 = W4[(k + 0) * 32 + tc];
    float4 w1 = W4[(k + 1) * 32 + tc];
    float4 w2 = W4[(k + 2) * 32 + tc];
    float4 w3 = W4[(k + 3) * 32 + tc];
    for (int i = 0; i < 8; i++) {
      float4 h4 = *((const float4*)&hs[(tr * 8 + i) * HDIM + k]);
      acc[i][0] += h4.x * w0.x + h4.y * w1.x + h4.z * w2.x + h4.w * w3.x;
      acc[i][1] += h4.x * w0.y + h4.y * w1.y + h4.z * w2.y + h4.w * w3.y;
      acc[i][2] += h4.x * w0.z + h4.y * w1.z + h4.z * w2.z + h4.w * w3.z;
      acc[i][3] += h4.x * w0.w + h4.y * w1.w + h4.z * w2.w + h4.w * w3.w;
    }
  }
  for (int i = 0; i < 8; i++) {
    int row = rowbase + tr * 8 + i;
    if (row < n) {
      float dv = dinv[row];
      ushort4 o;
      o.x = f2bf(acc[i][0] * dv);
      o.y = f2bf(acc[i][1] * dv);
      o.z = f2bf(acc[i][2] * dv);
      o.w = f2bf(acc[i][3] * dv);
      ((ushort4*)(Out + (size_t)row * HDIM))[tc] = o;
    }
  }
}

// ---------------- aggregation: one wave per dst node (bf16 T', fp32 accumulate) -------
// T' = dinv ⊙ (A·W) in bf16.  out = dinv[d]*(T'[d] + Σ T'[src]) + b.
// Lane holds cols {2*lane, 2*lane+1} as one packed uint (4B/lane, 256B/row).
// Indices for the NEXT pair are prefetched one iteration ahead so the exposed
// latency per iteration is only the row gather, not colx-load -> gather chained.
// MODE 0: + bias, relu, layernorm(g,b).   MODE 1: + bias only (emb output).
template <int MODE>
__global__ __launch_bounds__(256) void agg_k(const unsigned short* __restrict__ T,
                                             const int* __restrict__ rowptr,
                                             const int* __restrict__ colx,
                                             const float* __restrict__ dinv,
                                             const float* __restrict__ bias,
                                             const float* __restrict__ lng,
                                             const float* __restrict__ lnb,
                                             float* __restrict__ Out, int n) {
  int wid = (blockIdx.x * 256 + threadIdx.x) >> 6;
  int lane = threadIdx.x & 63;
  if (wid >= n) return;
  int i = wid;
  float di = dinv[i];
  const unsigned int* T32 = (const unsigned int*)T;  // 64 packed uints per row
  // self term
  unsigned int us = T32[(size_t)i * 64 + lane];
  float a0x = bf_lo(us), a0y = bf_hi(us);
  float a1x = 0.f, a1y = 0.f;
  int beg = rowptr[i], end = rowptr[i + 1];
  int e = beg;
  int c0 = 0, c1 = 0;
  if (e < end) c0 = colx[e];
  if (e + 1 < end) c1 = colx[e + 1];
  for (; e + 1 < end; e += 2) {
    unsigned int u0 = T32[(size_t)c0 * 64 + lane];
    unsigned int u1 = T32[(size_t)c1 * 64 + lane];
    // prefetch next pair's indices before consuming the gathers
    if (e + 2 < end) c0 = colx[e + 2];
    if (e + 3 < end) c1 = colx[e + 3];
    a0x += bf_lo(u0); a0y += bf_hi(u0);
    a1x += bf_lo(u1); a1y += bf_hi(u1);
  }
  if (e < end) {  // odd tail (c0 holds the right index by construction)
    unsigned int u0 = T32[(size_t)c0 * 64 + lane];
    a0x += bf_lo(u0); a0y += bf_hi(u0);
  }
  float2 bb = ((const float2*)bias)[lane];
  float2 acc;
  acc.x = (a0x + a1x) * di + bb.x;
  acc.y = (a0y + a1y) * di + bb.y;
  if (MODE == 0) {
    acc.x = fmaxf(acc.x, 0.f);
    acc.y = fmaxf(acc.y, 0.f);
    float s1 = acc.x + acc.y;
    float s2 = acc.x * acc.x + acc.y * acc.y;
    for (int off = 1; off < 64; off <<= 1) {
      s1 += __shfl_xor(s1, off);
      s2 += __shfl_xor(s2, off);
    }
    float mu = s1 * (1.f / 128.f);
    float var = s2 * (1.f / 128.f) - mu * mu;
    float r = rsqrtf(var + EPSLN);
    float2 gg = ((const float2*)lng)[lane];
    float2 b2 = ((const float2*)lnb)[lane];
    acc.x = (acc.x - mu) * r * gg.x + b2.x;
    acc.y = (acc.y - mu) * r * gg.y + b2.y;
  }
  ((float2*)(Out + (size_t)i * HDIM))[lane] = acc;
}

// ---------------- fused head: relu -> Linear(128) -> Linear(2) -> log_softmax ----------------
// Same register-blocked GEMM structure as gemm_k (W1 read once per BLOCK, not per node).
__global__ __launch_bounds__(256) void head_k(const float* __restrict__ emb,
                                              const float* __restrict__ W1_,
                                              const float* __restrict__ b1_,
                                              const float* __restrict__ W2_,
                                              const float* __restrict__ b2_,
                                              float* __restrict__ outp, int n) {
  __shared__ float hs[64 * HDIM];
  int t = threadIdx.x;
  int rowbase = blockIdx.x * 64;
  const float4* A4 = (const float4*)(emb + (size_t)rowbase * HDIM);
  for (int i = 0; i < 8; i++) {
    int fi = t + i * 256;
    int row = rowbase + (fi >> 5);
    float4 v = make_float4(0.f, 0.f, 0.f, 0.f);
    if (row < n) v = A4[fi];
    v.x = fmaxf(v.x, 0.f);  // relu while staging
    v.y = fmaxf(v.y, 0.f);
    v.z = fmaxf(v.z, 0.f);
    v.w = fmaxf(v.w, 0.f);
    ((float4*)hs)[fi] = v;
  }
  __syncthreads();

  int tc = t & 31;
  int tr = t >> 5;
  float acc[8][4];
  float4 binit = ((const float4*)b1_)[tc];
  for (int i = 0; i < 8; i++) {
    acc[i][0] = binit.x; acc[i][1] = binit.y; acc[i][2] = binit.z; acc[i][3] = binit.w;
  }

  const float4* W4 = (const float4*)W1_;
  for (int k = 0; k < HDIM; k += 4) {
    float4 w0 = W4[(k + 0) * 32 + tc];
    float4 w1 = W4[(k + 1) * 32 + tc];
    float4 w2 = W4[(k + 2) * 32 + tc];
    float4 w3 = W4[(k + 3) * 32 + tc];
    for (int i = 0; i < 8; i++) {
      float4 h4 = *((const float4*)&hs[(tr * 8 + i) * HDIM + k]);
      acc[i][0] += h4.x * w0.x + h4.y * w1.x + h4.z * w2.x + h4.w * w3.x;
      acc[i][1] += h4.x * w0.y + h4.y * w1.y + h4.z * w2.y + h4.w * w3.y;
      acc[i][2] += h4.x * w0.z + h4.y * w1.z + h4.z * w2.z + h4.w * w3.z;
      acc[i][3] += h4.x * w0.w + h4.y * w1.w + h4.z * w2.w + h4.w * w3.w;
    }
  }

  // second linear: z row dotted with W2 [128 x 2].  This thread owns cols 4*tc..4*tc+3.
  float2 w2c[4];
  for (int j = 0; j < 4; j++) w2c[j] = ((const float2*)W2_)[4 * tc + j];
  float o0[8], o1[8];
  for (int i = 0; i < 8; i++) {
    o0[i] = acc[i][0] * w2c[0].x + acc[i][1] * w2c[1].x + acc[i][2] * w2c[2].x + acc[i][3] * w2c[3].x;
    o1[i] = acc[i][0] * w2c[0].y + acc[i][1] * w2c[1].y + acc[i][2] * w2c[2].y + acc[i][3] * w2c[3].y;
  }
  // reduce across the 32 lanes sharing this tr (xor offsets < 32 stay within the half-wave)
  for (int off = 1; off < 32; off <<= 1) {
    for (int i = 0; i < 8; i++) {
      o0[i] += __shfl_xor(o0[i], off);
      o1[i] += __shfl_xor(o1[i], off);
    }
  }
  if (tc == 0) {
    float B0 = b2_[0], B1 = b2_[1];
    for (int i = 0; i < 8; i++) {
      int row = rowbase + tr * 8 + i;
      if (row < n) {
        float a = o0[i] + B0, b = o1[i] + B1;
        float m = fmaxf(a, b);
        float lse = m + logf(expf(a - m) + expf(b - m));
        outp[(size_t)row * 2 + 0] = a - lse;
        outp[(size_t)row * 2 + 1] = b - lse;
      }
    }
  }
}

// ---------------- launcher ----------------

extern "C" void kernel_launch(void* const* d_in, const int* in_sizes, int n_in,
                              void* d_out, int out_size, void* d_ws, size_t ws_size,
                              hipStream_t stream) {
  const float* x = (const float*)d_in[0];
  const int* ei = (const int*)d_in[1];
  const float* W1 = (const float*)d_in[2];
  const float* b1 = (const float*)d_in[3];
  const float* W2 = (const float*)d_in[4];
  const float* b2 = (const float*)d_in[5];
  const float* W3 = (const float*)d_in[6];
  const float* b3 = (const float*)d_in[7];
  const float* ln1g = (const float*)d_in[8];
  const float* ln1b = (const float*)d_in[9];
  const float* ln2g = (const float*)d_in[10];
  const float* ln2b = (const float*)d_in[11];
  const float* mpW1 = (const float*)d_in[12];
  const float* mpb1 = (const float*)d_in[13];
  const float* mpW2 = (const float*)d_in[14];
  const float* mpb2 = (const float*)d_in[15];

  const int N = in_sizes[0] / HDIM;
  const int E = in_sizes[1] / 2;
  const int* srcp = ei;
  const int* dstp = ei + E;

  // carve workspace
  char* p = (char*)d_ws;
  auto carve = [&](size_t bytes) {
    void* r = (void*)p;
    p += (bytes + 255) & ~(size_t)255;
    return r;
  };
  int* counts = (int*)carve((size_t)N * 4);
  int* rowptr = (int*)carve((size_t)(N + 1) * 4);
  int* cursor = (int*)carve((size_t)N * 4);
  int* bsum = (int*)carve(256 * 4);
  float* dinv = (float*)carve((size_t)N * 4);
  int* colx = (int*)carve((size_t)E * 4);
  unsigned short* bufT = (unsigned short*)carve((size_t)N * HDIM * 2);  // bf16 T'
  float* bufAct = (float*)carve((size_t)N * HDIM * 4);                  // fp32 activations

  float* emb = (float*)d_out;                    // N x 128
  float* logits = (float*)d_out + (size_t)N * HDIM;  // N x 2

  const int G = (N + 1023) / 1024;  // scan blocks (<= 256)

  hipMemsetAsync(counts, 0, (size_t)N * 4, stream);
  count_k<<<(E + 255) / 256, 256, 0, stream>>>(dstp, counts, E);
  dinv_k<<<(N + 255) / 256, 256, 0, stream>>>(counts, dinv, N);
  scan1_k<<<G, 256, 0, stream>>>(counts, bsum, N);
  scan2_k<<<1, 256, 0, stream>>>(bsum, rowptr, G, N);
  scan3_k<<<G, 256, 0, stream>>>(counts, bsum, rowptr, cursor, N);
  fill_k<<<(E + 255) / 256, 256, 0, stream>>>(srcp, dstp, cursor, colx, E);

  const int gemmG = (N + 63) / 64;
  const int aggG = (N * 64 + 255) / 256;

  // layer 1: x -> bufT (bf16, pre-scaled) -> (agg+relu+LN) bufAct
  gemm_k<<<gemmG, 256, 0, stream>>>(x, W1, dinv, bufT, N);
  agg_k<0><<<aggG, 256, 0, stream>>>(bufT, rowptr, colx, dinv, b1, ln1g, ln1b, bufAct, N);
  // layer 2
  gemm_k<<<gemmG, 256, 0, stream>>>(bufAct, W2, dinv, bufT, N);
  agg_k<0><<<aggG, 256, 0, stream>>>(bufT, rowptr, colx, dinv, b2, ln2g, ln2b, bufAct, N);
  // layer 3 -> emb (pre-relu) straight into d_out
  gemm_k<<<gemmG, 256, 0, stream>>>(bufAct, W3, dinv, bufT, N);
  agg_k<1><<<aggG, 256, 0, stream>>>(bufT, rowptr, colx, dinv, b3, nullptr, nullptr, emb, N);
  // head (register-blocked, fused log-softmax)
  head_k<<<gemmG, 256, 0, stream>>>(emb, mpW1, mpb1, mpW2, mpb2, logits, N);
}